// Round 1
// baseline (412.786 us; speedup 1.0000x reference)
//
#include <hip/hip_runtime.h>
#include <hip/hip_bf16.h>

// Elementwise: y = (x + 1) * 2 / 3; out = (y > 0) ? y - 5 : y
// 8192*8192 fp32 = 64M elems. Memory-bound: 512 MB traffic, roofline ~81 us.
// One thread per float4 (16B/lane coalescing sweet spot).

__global__ __launch_bounds__(256) void ew_kernel(const float4* __restrict__ x,
                                                 float4* __restrict__ out,
                                                 int n4) {
    int i = blockIdx.x * blockDim.x + threadIdx.x;
    if (i >= n4) return;
    float4 v = x[i];
    const float c = 2.0f / 3.0f;
    float4 r;
    r.x = (v.x + 1.0f) * c;
    r.y = (v.y + 1.0f) * c;
    r.z = (v.z + 1.0f) * c;
    r.w = (v.w + 1.0f) * c;
    r.x = (r.x > 0.0f) ? r.x - 5.0f : r.x;
    r.y = (r.y > 0.0f) ? r.y - 5.0f : r.y;
    r.z = (r.z > 0.0f) ? r.z - 5.0f : r.z;
    r.w = (r.w > 0.0f) ? r.w - 5.0f : r.w;
    out[i] = r;
}

extern "C" void kernel_launch(void* const* d_in, const int* in_sizes, int n_in,
                              void* d_out, int out_size, void* d_ws, size_t ws_size,
                              hipStream_t stream) {
    const float4* x = (const float4*)d_in[0];
    float4* out = (float4*)d_out;
    int n = in_sizes[0];          // 67108864, divisible by 4
    int n4 = n / 4;               // 16777216
    int block = 256;
    int grid = (n4 + block - 1) / block;
    ew_kernel<<<grid, block, 0, stream>>>(x, out, n4);
}